// Round 3
// baseline (221.975 us; speedup 1.0000x reference)
//
#include <hip/hip_runtime.h>
#include <math.h>

#define Bn 48
#define Ln 17
#define Dn 256
#define Mn 768        // Bn*(Ln-1)
#define NPAIR (Bn*Bn) // 2304
#define LDA 76        // LDS row stride: 304 B (16B-aligned rows, 2-way-max banks)

// exp(e) for e in [0, ~0.02]; rel err < 3e-15
static __device__ __forceinline__ double pexp(double e) {
  return 1.0 + e*(1.0 + e*(0.5 + e*((1.0/6.0) + e*((1.0/24.0) + e*(1.0/120.0)))));
}

static __device__ __forceinline__ double blockReduceSum256(double v, double* red) {
  #pragma unroll
  for (int o = 32; o > 0; o >>= 1) v += __shfl_down(v, o, 64);
  int lane = threadIdx.x & 63, wid = threadIdx.x >> 6;
  __syncthreads();
  if (lane == 0) red[wid] = v;
  __syncthreads();
  return red[0] + red[1] + red[2] + red[3];
}

// logical row m (0..815: 48 anchors then 768 tokens) -> row in x (B,L,D)
static __device__ __forceinline__ int src_row_m(int m) {
  if (m < Bn) return m * Ln;                 // (b, l=0)
  int t = m - Bn;
  return (t >> 4) * Ln + (t & 15) + 1;       // (b, l=1..16)
}
static __device__ __forceinline__ int src_row_n(int n) {
  return (n >> 4) * Ln + (n & 15) + 1;
}

// ---------- kA: fused normalize + GEMM + exp epilogue; also zero acc/done ----
// Tile 64x64, 256 threads, 4x4 outputs/thread, K staged 16 at a time in LDS.
__global__ __launch_bounds__(256) void kA_gemm(const float* __restrict__ x,
                                               double* __restrict__ EA,
                                               double* __restrict__ E,
                                               double* __restrict__ acc,
                                               unsigned int* __restrict__ done) {
  __shared__ float As[16][LDA];
  __shared__ float Bs[16][LDA];
  __shared__ float nA[64], nB[64];
  int tid = threadIdx.x;
  if (blockIdx.x == 0 && blockIdx.y == 0) {
    if (tid < Bn) acc[tid] = 0.0;
    else if (tid == Bn) *done = 0u;
  }
  int m0 = blockIdx.y * 64, n0 = blockIdx.x * 64;
  int r  = tid >> 2, cq = tid & 3;           // staging: row r, 16B chunk cq
  int mrow = m0 + r;
  int gm = (mrow < 816) ? src_row_m(mrow) : 0;
  int gn = src_row_n(n0 + r);
  const float* pa = x + gm * Dn + cq * 4;
  const float* pb = x + gn * Dn + cq * 4;
  float4 ra = *(const float4*)pa;
  float4 rb = *(const float4*)pb;
  float ssa = 0.f, ssb = 0.f;
  float c[4][4];
  #pragma unroll
  for (int i = 0; i < 4; ++i)
    #pragma unroll
    for (int j = 0; j < 4; ++j) c[i][j] = 0.f;
  int tx = tid & 15, ty = tid >> 4;

  for (int t = 0; t < 16; ++t) {
    __syncthreads();
    int kb = cq * 4;
    As[kb+0][r] = ra.x; As[kb+1][r] = ra.y; As[kb+2][r] = ra.z; As[kb+3][r] = ra.w;
    Bs[kb+0][r] = rb.x; Bs[kb+1][r] = rb.y; Bs[kb+2][r] = rb.z; Bs[kb+3][r] = rb.w;
    ssa += ra.x*ra.x + ra.y*ra.y + ra.z*ra.z + ra.w*ra.w;
    ssb += rb.x*rb.x + rb.y*rb.y + rb.z*rb.z + rb.w*rb.w;
    __syncthreads();
    if (t < 15) {                            // prefetch next k-tile into regs
      ra = *(const float4*)(pa + (t + 1) * 16);
      rb = *(const float4*)(pb + (t + 1) * 16);
    }
    #pragma unroll
    for (int k = 0; k < 16; ++k) {
      float4 a4 = *(const float4*)&As[k][ty * 4];
      float4 b4 = *(const float4*)&Bs[k][tx * 4];
      float av[4] = {a4.x, a4.y, a4.z, a4.w};
      float bv[4] = {b4.x, b4.y, b4.z, b4.w};
      #pragma unroll
      for (int i = 0; i < 4; ++i)
        #pragma unroll
        for (int j = 0; j < 4; ++j) c[i][j] = fmaf(av[i], bv[j], c[i][j]);
    }
  }
  // row norms: reduce squares over the 4 staging lanes of each row
  ssa += __shfl_xor(ssa, 1, 64); ssa += __shfl_xor(ssa, 2, 64);
  ssb += __shfl_xor(ssb, 1, 64); ssb += __shfl_xor(ssb, 2, 64);
  if (cq == 0) { nA[r] = ssa; nB[r] = ssb; }
  __syncthreads();
  double ia[4], ib[4];
  #pragma unroll
  for (int i = 0; i < 4; ++i) ia[i] = 1.0 / sqrt((double)nA[ty * 4 + i]);
  #pragma unroll
  for (int j = 0; j < 4; ++j) ib[j] = 1.0 / sqrt((double)nB[tx * 4 + j]);
  #pragma unroll
  for (int i = 0; i < 4; ++i) {
    int m = m0 + ty * 4 + i;
    if (m >= 816) continue;
    #pragma unroll
    for (int j = 0; j < 4; ++j) {
      int n = n0 + tx * 4 + j;
      double ev = exp((double)c[i][j] * ia[i] * ib[j]);   // T = 1.0
      if (m < Bn) EA[m * Mn + n] = ev;
      else        E[(m - Bn) * Mn + n] = ev;
    }
  }
}

// ---------- kB: per-pair (i,bj) setup + symmetric KL + last-block finalize ----
__global__ __launch_bounds__(256) void kB_pairs(const double* __restrict__ EA,
                                                const double* __restrict__ E,
                                                const int* __restrict__ label,
                                                double* __restrict__ acc,
                                                unsigned int* __restrict__ done,
                                                float* __restrict__ out) {
  __shared__ double sea[Mn];
  __shared__ double sa[Mn];    // a[k] = ci*ea[k] (masked)
  __shared__ double spa[Mn];   // pexp(a[k])     (masked)
  __shared__ double red[4];
  __shared__ int lab[Bn];
  __shared__ int lastFlag;
  int tid = threadIdx.x;
  int i = blockIdx.x / Bn, bj = blockIdx.x % Bn;
  if (tid < Bn) lab[tid] = label[tid];
  __syncthreads();
  int li = lab[i];
  bool active = (lab[bj] == li);

  if (active) {
    const double* ea = EA + i * Mn;
    double s1 = 0.0;
    for (int k = tid; k < Mn; k += 256) {
      double v = ea[k];
      sea[k] = v;
      if (lab[k >> 4] != li) s1 += v;
    }
    s1 = blockReduceSum256(s1, red);
    double ci = 1.0 / s1;                    // exp(-log_denom)

    double t2a = 0.0, t2b = 0.0;
    for (int k = tid; k < Mn; k += 256) {
      bool neg = (lab[k >> 4] != li);
      double a = ci * sea[k];
      double p = pexp(a);
      sa[k]  = neg ? a : 0.0;
      spa[k] = neg ? p : 0.0;
      if (neg) { t2a += p; t2b += p * a; }
    }
    t2a = blockReduceSum256(t2a, red);
    t2b = blockReduceSum256(t2b, red);
    double inv_s2 = 1.0 / t2a;
    double Evi = t2b * inv_s2;
    __syncthreads();

    int lane = tid & 63, wave = tid >> 6;
    double tsum = 0.0;
    #pragma unroll
    for (int jj = 0; jj < 4; ++jj) {
      int j = bj * 16 + wave * 4 + jj;
      const double* Ej = E + j * Mn;
      double A = 0.0, Bv = 0.0, C = 0.0, D2 = 0.0;
      for (int k = lane; k < Mn; k += 64) {
        if (lab[k >> 4] != li) {
          double e = ci * Ej[k];
          double w = pexp(e);
          A  = fma(w, e, A);
          Bv = fma(w, sa[k], Bv);
          C += w;
          D2 = fma(spa[k], e, D2);
        }
      }
      #pragma unroll
      for (int o = 32; o > 0; o >>= 1) {
        A  += __shfl_xor(A,  o, 64);
        Bv += __shfl_xor(Bv, o, 64);
        C  += __shfl_xor(C,  o, 64);
        D2 += __shfl_xor(D2, o, 64);
      }
      tsum += (A - Bv) / C - D2 * inv_s2 + Evi;
    }
    if (lane == 0) atomicAdd(&acc[i], 0.5 * tsum);
    __syncthreads();
  }

  // completion protocol: last of 2304 blocks finalizes
  __threadfence();
  if (tid == 0) {
    unsigned int old = atomicAdd(done, 1u);
    lastFlag = (old == NPAIR - 1) ? 1 : 0;
  }
  __syncthreads();
  if (lastFlag) {
    __threadfence();
    double v = 0.0;
    if (tid < Bn) {
      int lt = lab[tid];
      int cnt = 0;
      for (int b = 0; b < Bn; ++b) cnt += (lab[b] == lt) ? 1 : 0;
      double ai = atomicAdd(&acc[tid], 0.0);   // coherent read
      v = ai / (16.0 * (double)cnt);           // P_i = (L-1)*cnt
    }
    v = blockReduceSum256(v, red);
    if (tid == 0) out[0] = (float)(v / (double)Bn);
  }
}

extern "C" void kernel_launch(void* const* d_in, const int* in_sizes, int n_in,
                              void* d_out, int out_size, void* d_ws, size_t ws_size,
                              hipStream_t stream) {
  const float* x   = (const float*)d_in[0];
  const int* label = (const int*)d_in[1];
  float* out = (float*)d_out;

  char* ws = (char*)d_ws;
  size_t off = 0;
  auto alloc = [&](size_t bytes) -> void* {
    void* p = ws + off;
    off = (off + bytes + 255) & ~(size_t)255;
    return p;
  };
  double* EA   = (double*)alloc((size_t)Bn * Mn * sizeof(double));
  double* E    = (double*)alloc((size_t)Mn * Mn * sizeof(double));
  double* acc  = (double*)alloc((size_t)Bn * sizeof(double));
  unsigned int* done = (unsigned int*)alloc(sizeof(unsigned int));

  kA_gemm<<<dim3(12, 13), 256, 0, stream>>>(x, EA, E, acc, done);
  kB_pairs<<<NPAIR, 256, 0, stream>>>(EA, E, label, acc, done, out);
}

// Round 4
// 150.763 us; speedup vs baseline: 1.4723x; 1.4723x over previous
//
#include <hip/hip_runtime.h>
#include <math.h>

#define Bn 48
#define Ln 17
#define Dn 256
#define Mn 768        // Bn*(Ln-1)
#define NSLICE 4
#define LDA 76        // LDS row stride for kA staging

// exp(e) for e in [0, ~0.02]; rel err < 3e-15
static __device__ __forceinline__ double pexp(double e) {
  return 1.0 + e*(1.0 + e*(0.5 + e*((1.0/6.0) + e*((1.0/24.0) + e*(1.0/120.0)))));
}

static __device__ __forceinline__ double blockReduceSum256(double v, double* red) {
  #pragma unroll
  for (int o = 32; o > 0; o >>= 1) v += __shfl_down(v, o, 64);
  int lane = threadIdx.x & 63, wid = threadIdx.x >> 6;
  __syncthreads();
  if (lane == 0) red[wid] = v;
  __syncthreads();
  return red[0] + red[1] + red[2] + red[3];
}

// logical row m (0..815: 48 anchors then 768 tokens) -> row in x (B,L,D)
static __device__ __forceinline__ int src_row_m(int m) {
  if (m < Bn) return m * Ln;                 // (b, l=0)
  int t = m - Bn;
  return (t >> 4) * Ln + (t & 15) + 1;       // (b, l=1..16)
}
static __device__ __forceinline__ int src_row_n(int n) {
  return (n >> 4) * Ln + (n & 15) + 1;
}

// ---------- kA: fused normalize + GEMM + exp epilogue ----------
// Tile 64x64, 256 threads, 4x4 outputs/thread, K staged 16 at a time in LDS.
__global__ __launch_bounds__(256) void kA_gemm(const float* __restrict__ x,
                                               double* __restrict__ EA,
                                               double* __restrict__ E) {
  __shared__ float As[16][LDA];
  __shared__ float Bs[16][LDA];
  __shared__ float nA[64], nB[64];
  int tid = threadIdx.x;
  int m0 = blockIdx.y * 64, n0 = blockIdx.x * 64;
  int r  = tid >> 2, cq = tid & 3;           // staging: row r, 16B chunk cq
  int mrow = m0 + r;
  int gm = (mrow < 816) ? src_row_m(mrow) : 0;
  int gn = src_row_n(n0 + r);
  const float* pa = x + gm * Dn + cq * 4;
  const float* pb = x + gn * Dn + cq * 4;
  float4 ra = *(const float4*)pa;
  float4 rb = *(const float4*)pb;
  float ssa = 0.f, ssb = 0.f;
  float c[4][4];
  #pragma unroll
  for (int i = 0; i < 4; ++i)
    #pragma unroll
    for (int j = 0; j < 4; ++j) c[i][j] = 0.f;
  int tx = tid & 15, ty = tid >> 4;

  for (int t = 0; t < 16; ++t) {
    __syncthreads();
    int kb = cq * 4;
    As[kb+0][r] = ra.x; As[kb+1][r] = ra.y; As[kb+2][r] = ra.z; As[kb+3][r] = ra.w;
    Bs[kb+0][r] = rb.x; Bs[kb+1][r] = rb.y; Bs[kb+2][r] = rb.z; Bs[kb+3][r] = rb.w;
    ssa += ra.x*ra.x + ra.y*ra.y + ra.z*ra.z + ra.w*ra.w;
    ssb += rb.x*rb.x + rb.y*rb.y + rb.z*rb.z + rb.w*rb.w;
    __syncthreads();
    if (t < 15) {                            // prefetch next k-tile into regs
      ra = *(const float4*)(pa + (t + 1) * 16);
      rb = *(const float4*)(pb + (t + 1) * 16);
    }
    #pragma unroll
    for (int k = 0; k < 16; ++k) {
      float4 a4 = *(const float4*)&As[k][ty * 4];
      float4 b4 = *(const float4*)&Bs[k][tx * 4];
      float av[4] = {a4.x, a4.y, a4.z, a4.w};
      float bv[4] = {b4.x, b4.y, b4.z, b4.w};
      #pragma unroll
      for (int i = 0; i < 4; ++i)
        #pragma unroll
        for (int j = 0; j < 4; ++j) c[i][j] = fmaf(av[i], bv[j], c[i][j]);
    }
  }
  // row norms: reduce squares over the 4 staging lanes of each row
  ssa += __shfl_xor(ssa, 1, 64); ssa += __shfl_xor(ssa, 2, 64);
  ssb += __shfl_xor(ssb, 1, 64); ssb += __shfl_xor(ssb, 2, 64);
  if (cq == 0) { nA[r] = ssa; nB[r] = ssb; }
  __syncthreads();
  double ia[4], ib[4];
  #pragma unroll
  for (int i = 0; i < 4; ++i) ia[i] = 1.0 / sqrt((double)nA[ty * 4 + i]);
  #pragma unroll
  for (int j = 0; j < 4; ++j) ib[j] = 1.0 / sqrt((double)nB[tx * 4 + j]);
  #pragma unroll
  for (int i = 0; i < 4; ++i) {
    int m = m0 + ty * 4 + i;
    if (m >= 816) continue;
    #pragma unroll
    for (int j = 0; j < 4; ++j) {
      int n = n0 + tx * 4 + j;
      double ev = exp((double)c[i][j] * ia[i] * ib[j]);   // T = 1.0
      if (m < Bn) EA[m * Mn + n] = ev;
      else        E[(m - Bn) * Mn + n] = ev;
    }
  }
}

// ---------- kB: per (slice, i): setup + symmetric KL over positive batches ----
// t(i,j) = (A - Bv)/C - D2*inv_s2 + Evi ; acc2[i*4+slice] = sum_j t(i,j)
__global__ __launch_bounds__(256) void kB_i(const double* __restrict__ EA,
                                            const double* __restrict__ E,
                                            const int* __restrict__ label,
                                            double* __restrict__ acc2) {
  __shared__ double sa[Mn];    // a[k] = ci*ea[k] (masked)
  __shared__ double spa[Mn];   // pexp(a[k])     (masked)
  __shared__ double red[4];
  __shared__ int lab[Bn];
  int tid = threadIdx.x;
  int slice = blockIdx.x, i = blockIdx.y;
  if (tid < Bn) lab[tid] = label[tid];
  __syncthreads();
  int li = lab[i];
  const double* ea = EA + i * Mn;

  double s1 = 0.0;
  for (int k = tid; k < Mn; k += 256)
    if (lab[k >> 4] != li) s1 += ea[k];
  s1 = blockReduceSum256(s1, red);
  double ci = 1.0 / s1;                      // exp(-log_denom)

  double t2a = 0.0, t2b = 0.0;
  for (int k = tid; k < Mn; k += 256) {
    bool neg = (lab[k >> 4] != li);
    double a = ci * ea[k];
    double p = pexp(a);
    sa[k]  = neg ? a : 0.0;
    spa[k] = neg ? p : 0.0;
    if (neg) { t2a += p; t2b += p * a; }
  }
  t2a = blockReduceSum256(t2a, red);
  t2b = blockReduceSum256(t2b, red);
  double inv_s2 = 1.0 / t2a;
  double Evi = t2b * inv_s2;

  int lane = tid & 63, wave = tid >> 6;
  double tsum = 0.0;
  for (int bj = slice; bj < Bn; bj += NSLICE) {
    if (lab[bj] != li) continue;             // only positive batches
    #pragma unroll
    for (int jj = 0; jj < 4; ++jj) {
      int j = bj * 16 + wave * 4 + jj;
      const double* Ej = E + j * Mn;
      double A = 0.0, Bv = 0.0, C = 0.0, D2 = 0.0;
      for (int k = lane; k < Mn; k += 64) {
        if (lab[k >> 4] != li) {
          double e = ci * Ej[k];
          double w = pexp(e);
          A  = fma(w, e, A);
          Bv = fma(w, sa[k], Bv);
          C += w;
          D2 = fma(spa[k], e, D2);
        }
      }
      #pragma unroll
      for (int o = 32; o > 0; o >>= 1) {
        A  += __shfl_xor(A,  o, 64);
        Bv += __shfl_xor(Bv, o, 64);
        C  += __shfl_xor(C,  o, 64);
        D2 += __shfl_xor(D2, o, 64);
      }
      tsum += (A - Bv) / C - D2 * inv_s2 + Evi;
    }
  }
  __syncthreads();                           // red[] reuse + laggard waves
  if (lane == 0) red[wave] = tsum;
  __syncthreads();
  if (tid == 0) acc2[i * NSLICE + slice] = red[0] + red[1] + red[2] + red[3];
}

// ---------- kC: loss = 0.5/Bn * sum_{i,s} acc2[i,s] / P_i ----------
__global__ __launch_bounds__(256) void kC_final(const double* __restrict__ acc2,
                                                const int* __restrict__ label,
                                                float* __restrict__ out) {
  __shared__ double red[4];
  __shared__ int lab[Bn];
  int tid = threadIdx.x;
  if (tid < Bn) lab[tid] = label[tid];
  __syncthreads();
  double v = 0.0;
  if (tid < Bn * NSLICE) {
    int i = tid >> 2;
    int li = lab[i];
    int cnt = 0;
    for (int b = 0; b < Bn; ++b) cnt += (lab[b] == li) ? 1 : 0;
    v = acc2[tid] / (16.0 * (double)cnt);    // P_i = (L-1)*cnt
  }
  v = blockReduceSum256(v, red);
  if (tid == 0) out[0] = (float)(0.5 * v / (double)Bn);
}

extern "C" void kernel_launch(void* const* d_in, const int* in_sizes, int n_in,
                              void* d_out, int out_size, void* d_ws, size_t ws_size,
                              hipStream_t stream) {
  const float* x   = (const float*)d_in[0];
  const int* label = (const int*)d_in[1];
  float* out = (float*)d_out;

  char* ws = (char*)d_ws;
  size_t off = 0;
  auto alloc = [&](size_t bytes) -> void* {
    void* p = ws + off;
    off = (off + bytes + 255) & ~(size_t)255;
    return p;
  };
  double* EA   = (double*)alloc((size_t)Bn * Mn * sizeof(double));
  double* E    = (double*)alloc((size_t)Mn * Mn * sizeof(double));
  double* acc2 = (double*)alloc((size_t)Bn * NSLICE * sizeof(double));

  kA_gemm<<<dim3(12, 13), 256, 0, stream>>>(x, EA, E);
  kB_i<<<dim3(NSLICE, Bn), 256, 0, stream>>>(EA, E, label, acc2);
  kC_final<<<1, 256, 0, stream>>>(acc2, label, out);
}

// Round 5
// 116.597 us; speedup vs baseline: 1.9038x; 1.2930x over previous
//
#include <hip/hip_runtime.h>
#include <math.h>

#define Bn 48
#define Ln 17
#define Dn 256
#define Mn 768        // Bn*(Ln-1)
#define LDA 76        // LDS row stride for kA staging

// exp(e) for e in [0, ~0.02]; rel err < 3e-15
static __device__ __forceinline__ double pexp(double e) {
  return 1.0 + e*(1.0 + e*(0.5 + e*((1.0/6.0) + e*((1.0/24.0) + e*(1.0/120.0)))));
}

static __device__ __forceinline__ double blockReduceSum256(double v, double* red) {
  #pragma unroll
  for (int o = 32; o > 0; o >>= 1) v += __shfl_down(v, o, 64);
  int lane = threadIdx.x & 63, wid = threadIdx.x >> 6;
  __syncthreads();
  if (lane == 0) red[wid] = v;
  __syncthreads();
  return red[0] + red[1] + red[2] + red[3];
}

// logical row m (0..815: 48 anchors then 768 tokens) -> row in x (B,L,D)
static __device__ __forceinline__ int src_row_m(int m) {
  if (m < Bn) return m * Ln;                 // (b, l=0)
  int t = m - Bn;
  return (t >> 4) * Ln + (t & 15) + 1;       // (b, l=1..16)
}
static __device__ __forceinline__ int src_row_n(int n) {
  return (n >> 4) * Ln + (n & 15) + 1;
}

// ---------- kA: fused normalize + GEMM + exp epilogue ----------
__global__ __launch_bounds__(256) void kA_gemm(const float* __restrict__ x,
                                               double* __restrict__ EA,
                                               double* __restrict__ E) {
  __shared__ float As[16][LDA];
  __shared__ float Bs[16][LDA];
  __shared__ float nA[64], nB[64];
  int tid = threadIdx.x;
  int m0 = blockIdx.y * 64, n0 = blockIdx.x * 64;
  int r  = tid >> 2, cq = tid & 3;
  int mrow = m0 + r;
  int gm = (mrow < 816) ? src_row_m(mrow) : 0;
  int gn = src_row_n(n0 + r);
  const float* pa = x + gm * Dn + cq * 4;
  const float* pb = x + gn * Dn + cq * 4;
  float4 ra = *(const float4*)pa;
  float4 rb = *(const float4*)pb;
  float ssa = 0.f, ssb = 0.f;
  float c[4][4];
  #pragma unroll
  for (int i = 0; i < 4; ++i)
    #pragma unroll
    for (int j = 0; j < 4; ++j) c[i][j] = 0.f;
  int tx = tid & 15, ty = tid >> 4;

  for (int t = 0; t < 16; ++t) {
    __syncthreads();
    int kb = cq * 4;
    As[kb+0][r] = ra.x; As[kb+1][r] = ra.y; As[kb+2][r] = ra.z; As[kb+3][r] = ra.w;
    Bs[kb+0][r] = rb.x; Bs[kb+1][r] = rb.y; Bs[kb+2][r] = rb.z; Bs[kb+3][r] = rb.w;
    ssa += ra.x*ra.x + ra.y*ra.y + ra.z*ra.z + ra.w*ra.w;
    ssb += rb.x*rb.x + rb.y*rb.y + rb.z*rb.z + rb.w*rb.w;
    __syncthreads();
    if (t < 15) {
      ra = *(const float4*)(pa + (t + 1) * 16);
      rb = *(const float4*)(pb + (t + 1) * 16);
    }
    #pragma unroll
    for (int k = 0; k < 16; ++k) {
      float4 a4 = *(const float4*)&As[k][ty * 4];
      float4 b4 = *(const float4*)&Bs[k][tx * 4];
      float av[4] = {a4.x, a4.y, a4.z, a4.w};
      float bv[4] = {b4.x, b4.y, b4.z, b4.w};
      #pragma unroll
      for (int i = 0; i < 4; ++i)
        #pragma unroll
        for (int j = 0; j < 4; ++j) c[i][j] = fmaf(av[i], bv[j], c[i][j]);
    }
  }
  ssa += __shfl_xor(ssa, 1, 64); ssa += __shfl_xor(ssa, 2, 64);
  ssb += __shfl_xor(ssb, 1, 64); ssb += __shfl_xor(ssb, 2, 64);
  if (cq == 0) { nA[r] = ssa; nB[r] = ssb; }
  __syncthreads();
  double ia[4], ib[4];
  #pragma unroll
  for (int i = 0; i < 4; ++i) ia[i] = 1.0 / sqrt((double)nA[ty * 4 + i]);
  #pragma unroll
  for (int j = 0; j < 4; ++j) ib[j] = 1.0 / sqrt((double)nB[tx * 4 + j]);
  #pragma unroll
  for (int i = 0; i < 4; ++i) {
    int m = m0 + ty * 4 + i;
    if (m >= 816) continue;
    #pragma unroll
    for (int j = 0; j < 4; ++j) {
      int n = n0 + tx * 4 + j;
      double ev = exp((double)c[i][j] * ia[i] * ib[j]);   // T = 1.0
      if (m < Bn) EA[m * Mn + n] = ev;
      else        E[(m - Bn) * Mn + n] = ev;
    }
  }
}

// ---------- kS: per-i tables: sa (masked logits), spn (=sm_a), ci, Evi, negmask
__global__ __launch_bounds__(256) void kS_setup(const double* __restrict__ EA,
                                                const int* __restrict__ label,
                                                double* __restrict__ sa_g,
                                                double* __restrict__ spn_g,
                                                double* __restrict__ ci_g,
                                                double* __restrict__ Ev_g,
                                                unsigned long long* __restrict__ nm_g) {
  __shared__ double red[4];
  __shared__ int lab[64];
  int i = blockIdx.x, tid = threadIdx.x;
  if (tid < 64) lab[tid] = (tid < Bn) ? label[tid] : label[0];
  __syncthreads();
  int li = lab[i];
  const double* ea = EA + i * Mn;

  double s1 = 0.0;
  for (int k = tid; k < Mn; k += 256)
    if (lab[k >> 4] != li) s1 += ea[k];
  s1 = blockReduceSum256(s1, red);
  double ci = 1.0 / s1;                      // exp(-log_denom)

  double t2a = 0.0, t2b = 0.0;
  for (int k = tid; k < Mn; k += 256) {
    bool neg = (lab[k >> 4] != li);
    double a = ci * ea[k];
    double p = pexp(a);
    if (neg) { t2a += p; t2b += p * a; }
  }
  t2a = blockReduceSum256(t2a, red);
  t2b = blockReduceSum256(t2b, red);
  double inv_s2 = 1.0 / t2a;

  for (int k = tid; k < Mn; k += 256) {
    bool neg = (lab[k >> 4] != li);
    double a = ci * ea[k];
    sa_g [i * Mn + k] = neg ? a : 0.0;
    spn_g[i * Mn + k] = neg ? pexp(a) * inv_s2 : 0.0;   // sm_a
  }
  if (tid < 64) {
    bool p = (tid < Bn) && (lab[tid] != li);
    unsigned long long bm = __ballot(p);
    if (tid == 0) { ci_g[i] = ci; Ev_g[i] = t2b * inv_s2; nm_g[i] = bm; }
  }
}

// ---------- kB: one wave per (i,j); grid (bj, i), 1024 thr = 16 j per block ----
__global__ __launch_bounds__(1024, 4) void kB_pairs(const double* __restrict__ E,
                                                    const double* __restrict__ sa_g,
                                                    const double* __restrict__ spn_g,
                                                    const double* __restrict__ ci_g,
                                                    const double* __restrict__ Ev_g,
                                                    const unsigned long long* __restrict__ nm_g,
                                                    const int* __restrict__ label,
                                                    double* __restrict__ tj_g) {
  int bj = blockIdx.x, i = blockIdx.y;
  if (label[bj] != label[i]) return;         // only positive batches
  int tid = threadIdx.x;
  int w = tid >> 6, lane = tid & 63;
  int j = bj * 16 + w;
  const double* Ej  = E     + j * Mn + lane;
  const double* sar = sa_g  + i * Mn + lane;
  const double* spr = spn_g + i * Mn + lane;
  unsigned long long nm = nm_g[i];
  double ci = ci_g[i], Evi = Ev_g[i];

  double Evv[12], Sv[12], Pv[12];
  #pragma unroll
  for (int it = 0; it < 12; ++it) Evv[it] = Ej[64 * it];
  #pragma unroll
  for (int it = 0; it < 12; ++it) Sv[it] = sar[64 * it];
  #pragma unroll
  for (int it = 0; it < 12; ++it) Pv[it] = spr[64 * it];

  double A = 0.0, Bv = 0.0, C = 0.0, D2 = 0.0;
  int kb0 = lane >> 4;
  #pragma unroll
  for (int it = 0; it < 12; ++it) {
    double m = (double)((nm >> (kb0 + 4 * it)) & 1ull);
    double e = ci * Evv[it];
    double wx = pexp(e);
    double wm = wx * m;
    A  = fma(wm, e, A);
    Bv = fma(wx, Sv[it], Bv);                // Sv pre-masked
    C += wm;
    D2 = fma(Pv[it], e, D2);                 // Pv pre-masked & normalized
  }
  #pragma unroll
  for (int o = 32; o > 0; o >>= 1) {
    A  += __shfl_xor(A,  o, 64);
    Bv += __shfl_xor(Bv, o, 64);
    C  += __shfl_xor(C,  o, 64);
    D2 += __shfl_xor(D2, o, 64);
  }
  if (lane == 0)
    tj_g[(i * Bn + bj) * 16 + w] = (A - Bv) / C - D2 + Evi;
}

// ---------- kC: loss = 0.5/Bn * sum over positive (i,j) of t / P_i ----------
__global__ __launch_bounds__(256) void kC_final(const double* __restrict__ tj_g,
                                                const int* __restrict__ label,
                                                float* __restrict__ out) {
  __shared__ double red[4];
  __shared__ int lab[Bn];
  __shared__ double pinv[Bn];
  int tid = threadIdx.x;
  if (tid < Bn) lab[tid] = label[tid];
  __syncthreads();
  if (tid < Bn) {
    int c = 0;
    for (int b = 0; b < Bn; ++b) c += (lab[b] == lab[tid]) ? 1 : 0;
    pinv[tid] = 1.0 / (16.0 * (double)c);    // 1/P_i
  }
  __syncthreads();
  double v = 0.0;
  for (int idx = tid; idx < Bn * Bn * 16; idx += 256) {
    int i = idx / (Bn * 16);
    int r = idx - i * (Bn * 16);
    int bj = r >> 4;
    if (lab[bj] == lab[i]) v += tj_g[idx] * pinv[i];   // skip poison entries
  }
  v = blockReduceSum256(v, red);
  if (tid == 0) out[0] = (float)(0.5 * v / (double)Bn);
}

extern "C" void kernel_launch(void* const* d_in, const int* in_sizes, int n_in,
                              void* d_out, int out_size, void* d_ws, size_t ws_size,
                              hipStream_t stream) {
  const float* x   = (const float*)d_in[0];
  const int* label = (const int*)d_in[1];
  float* out = (float*)d_out;

  char* ws = (char*)d_ws;
  size_t off = 0;
  auto alloc = [&](size_t bytes) -> void* {
    void* p = ws + off;
    off = (off + bytes + 255) & ~(size_t)255;
    return p;
  };
  double* EA  = (double*)alloc((size_t)Bn * Mn * sizeof(double));
  double* E   = (double*)alloc((size_t)Mn * Mn * sizeof(double));
  double* sa  = (double*)alloc((size_t)Bn * Mn * sizeof(double));
  double* spn = (double*)alloc((size_t)Bn * Mn * sizeof(double));
  double* ci  = (double*)alloc((size_t)Bn * sizeof(double));
  double* Evv = (double*)alloc((size_t)Bn * sizeof(double));
  unsigned long long* nm = (unsigned long long*)alloc((size_t)Bn * sizeof(unsigned long long));
  double* tj  = (double*)alloc((size_t)Bn * Bn * 16 * sizeof(double));

  kA_gemm<<<dim3(12, 13), 256, 0, stream>>>(x, EA, E);
  kS_setup<<<Bn, 256, 0, stream>>>(EA, label, sa, spn, ci, Evv, nm);
  kB_pairs<<<dim3(Bn, Bn), 1024, 0, stream>>>(E, sa, spn, ci, Evv, nm, label, tj);
  kC_final<<<1, 256, 0, stream>>>(tj, label, out);
}

// Round 6
// 102.876 us; speedup vs baseline: 2.1577x; 1.1334x over previous
//
#include <hip/hip_runtime.h>
#include <math.h>

#define Bn 48
#define Ln 17
#define Dn 256
#define Mn 768        // Bn*(Ln-1)
#define LDA 76        // LDS row stride for kA staging

// exp(e) for e in [0, ~0.02]; rel err < 3e-15
static __device__ __forceinline__ double pexp(double e) {
  return 1.0 + e*(1.0 + e*(0.5 + e*((1.0/6.0) + e*((1.0/24.0) + e*(1.0/120.0)))));
}

// block-wide sum over 16 waves (1024 threads); safe for back-to-back reuse
static __device__ __forceinline__ double blockReduce16(double v, double* red) {
  __syncthreads();
  #pragma unroll
  for (int o = 32; o > 0; o >>= 1) v += __shfl_down(v, o, 64);
  int lane = threadIdx.x & 63, wid = threadIdx.x >> 6;
  if (lane == 0) red[wid] = v;
  __syncthreads();
  double r = 0.0;
  #pragma unroll
  for (int w = 0; w < 16; ++w) r += red[w];
  return r;
}

// logical row m (0..815: 48 anchors then 768 tokens) -> row in x (B,L,D)
static __device__ __forceinline__ int src_row_m(int m) {
  if (m < Bn) return m * Ln;                 // (b, l=0)
  int t = m - Bn;
  return (t >> 4) * Ln + (t & 15) + 1;       // (b, l=1..16)
}
static __device__ __forceinline__ int src_row_n(int n) {
  return (n >> 4) * Ln + (n & 15) + 1;
}

// ---------- kA: fused normalize + GEMM + exp epilogue ----------
// Tile 64x64, 256 threads, 4x4 outputs/thread, K staged 16 at a time in LDS.
__global__ __launch_bounds__(256) void kA_gemm(const float* __restrict__ x,
                                               double* __restrict__ EA,
                                               double* __restrict__ E) {
  __shared__ float As[16][LDA];
  __shared__ float Bs[16][LDA];
  __shared__ float nA[64], nB[64];
  int tid = threadIdx.x;
  int m0 = blockIdx.y * 64, n0 = blockIdx.x * 64;
  int r  = tid >> 2, cq = tid & 3;
  int mrow = m0 + r;
  int gm = (mrow < 816) ? src_row_m(mrow) : 0;
  int gn = src_row_n(n0 + r);
  const float* pa = x + gm * Dn + cq * 4;
  const float* pb = x + gn * Dn + cq * 4;
  float4 ra = *(const float4*)pa;
  float4 rb = *(const float4*)pb;
  float ssa = 0.f, ssb = 0.f;
  float c[4][4];
  #pragma unroll
  for (int i = 0; i < 4; ++i)
    #pragma unroll
    for (int j = 0; j < 4; ++j) c[i][j] = 0.f;
  int tx = tid & 15, ty = tid >> 4;

  for (int t = 0; t < 16; ++t) {
    __syncthreads();
    int kb = cq * 4;
    As[kb+0][r] = ra.x; As[kb+1][r] = ra.y; As[kb+2][r] = ra.z; As[kb+3][r] = ra.w;
    Bs[kb+0][r] = rb.x; Bs[kb+1][r] = rb.y; Bs[kb+2][r] = rb.z; Bs[kb+3][r] = rb.w;
    ssa += ra.x*ra.x + ra.y*ra.y + ra.z*ra.z + ra.w*ra.w;
    ssb += rb.x*rb.x + rb.y*rb.y + rb.z*rb.z + rb.w*rb.w;
    __syncthreads();
    if (t < 15) {
      ra = *(const float4*)(pa + (t + 1) * 16);
      rb = *(const float4*)(pb + (t + 1) * 16);
    }
    #pragma unroll
    for (int k = 0; k < 16; ++k) {
      float4 a4 = *(const float4*)&As[k][ty * 4];
      float4 b4 = *(const float4*)&Bs[k][tx * 4];
      float av[4] = {a4.x, a4.y, a4.z, a4.w};
      float bv[4] = {b4.x, b4.y, b4.z, b4.w};
      #pragma unroll
      for (int i = 0; i < 4; ++i)
        #pragma unroll
        for (int j = 0; j < 4; ++j) c[i][j] = fmaf(av[i], bv[j], c[i][j]);
    }
  }
  ssa += __shfl_xor(ssa, 1, 64); ssa += __shfl_xor(ssa, 2, 64);
  ssb += __shfl_xor(ssb, 1, 64); ssb += __shfl_xor(ssb, 2, 64);
  if (cq == 0) { nA[r] = ssa; nB[r] = ssb; }
  __syncthreads();
  double ia[4], ib[4];
  #pragma unroll
  for (int i = 0; i < 4; ++i) ia[i] = 1.0 / sqrt((double)nA[ty * 4 + i]);
  #pragma unroll
  for (int j = 0; j < 4; ++j) ib[j] = 1.0 / sqrt((double)nB[tx * 4 + j]);
  #pragma unroll
  for (int i = 0; i < 4; ++i) {
    int m = m0 + ty * 4 + i;
    if (m >= 816) continue;
    #pragma unroll
    for (int j = 0; j < 4; ++j) {
      int n = n0 + tx * 4 + j;
      double ev = exp((double)c[i][j] * ia[i] * ib[j]);   // T = 1.0
      if (m < Bn) EA[m * Mn + n] = ev;
      else        E[(m - Bn) * Mn + n] = ev;
    }
  }
}

// ---------- kB: per (i,bj) block: inline per-i setup + one wave per j ----------
// t(i,j) = (A - Bv)/C - D2*inv_s2 + Evi
__global__ __launch_bounds__(1024, 4) void kB_pairs(const double* __restrict__ EA,
                                                    const double* __restrict__ E,
                                                    const int* __restrict__ label,
                                                    double* __restrict__ tj_g) {
  int bj = blockIdx.x, i = blockIdx.y;
  int li = label[i];
  if (label[bj] != li) return;               // only positive batches

  __shared__ double2 sp[Mn];                 // {a masked, pexp(a) masked}
  __shared__ double red[16];
  __shared__ int lab[Bn];
  int tid = threadIdx.x;
  int lane = tid & 63, w = tid >> 6;
  if (tid < Bn) lab[tid] = label[tid];
  __syncthreads();

  // ---- per-i setup from EA row (tid<768 holds one element in-register) ----
  bool has = (tid < Mn);
  bool neg = has && (lab[tid >> 4] != li);
  double eav = has ? EA[i * Mn + tid] : 0.0;
  double s1 = blockReduce16(neg ? eav : 0.0, red);
  double ci = 1.0 / s1;                      // exp(-log_denom)
  double a = ci * eav;
  double p = pexp(a);
  if (has) { sp[tid].x = neg ? a : 0.0; sp[tid].y = neg ? p : 0.0; }
  double t2a = blockReduce16(neg ? p : 0.0, red);
  double t2b = blockReduce16(neg ? p * a : 0.0, red);
  double inv_s2 = 1.0 / t2a;
  double Evi = t2b * inv_s2;
  unsigned long long nm = __ballot(lane < Bn && lab[lane] != li);

  // ---- j-phase: wave w handles j = bj*16 + w; straight-line, no syncs ----
  int j = bj * 16 + w;
  const double* Ej = E + j * Mn + lane;
  double Evv[12];
  #pragma unroll
  for (int it = 0; it < 12; ++it) Evv[it] = Ej[64 * it];

  double A = 0.0, Bv = 0.0, C = 0.0, D2 = 0.0;
  int kb0 = lane >> 4;
  #pragma unroll
  for (int it = 0; it < 12; ++it) {
    double m = (double)((nm >> (kb0 + 4 * it)) & 1ull);
    double e = ci * Evv[it];
    double wx = pexp(e);
    double wm = wx * m;
    double2 s = sp[lane + 64 * it];
    A  = fma(wm, e, A);
    Bv = fma(wx, s.x, Bv);                   // s.x pre-masked
    C += wm;
    D2 = fma(s.y, e, D2);                    // s.y pre-masked
  }
  #pragma unroll
  for (int o = 32; o > 0; o >>= 1) {
    A  += __shfl_xor(A,  o, 64);
    Bv += __shfl_xor(Bv, o, 64);
    C  += __shfl_xor(C,  o, 64);
    D2 += __shfl_xor(D2, o, 64);
  }
  if (lane == 0)
    tj_g[(i * Bn + bj) * 16 + w] = (A - Bv) / C - D2 * inv_s2 + Evi;
}

// ---------- kC: loss = 0.5/Bn * sum over positive (i,j) of t / P_i ----------
__global__ __launch_bounds__(1024) void kC_final(const double* __restrict__ tj_g,
                                                 const int* __restrict__ label,
                                                 float* __restrict__ out) {
  __shared__ double red[16];
  __shared__ int lab[Bn];
  __shared__ double pinv[Bn];
  int tid = threadIdx.x;
  if (tid < Bn) lab[tid] = label[tid];
  __syncthreads();
  if (tid < Bn) {
    int c = 0;
    for (int b = 0; b < Bn; ++b) c += (lab[b] == lab[tid]) ? 1 : 0;
    pinv[tid] = 1.0 / (16.0 * (double)c);    // 1/P_i
  }
  __syncthreads();
  double v = 0.0;
  for (int idx = tid; idx < Bn * Bn * 16; idx += 1024) {
    int i = idx / (Bn * 16);
    int r = idx - i * (Bn * 16);
    int bj = r >> 4;
    if (lab[bj] == lab[i]) v += tj_g[idx] * pinv[i];   // skip poison entries
  }
  #pragma unroll
  for (int o = 32; o > 0; o >>= 1) v += __shfl_down(v, o, 64);
  int lane = tid & 63, wid = tid >> 6;
  if (lane == 0) red[wid] = v;
  __syncthreads();
  if (tid == 0) {
    double s = 0.0;
    #pragma unroll
    for (int w = 0; w < 16; ++w) s += red[w];
    out[0] = (float)(0.5 * s / (double)Bn);
  }
}

extern "C" void kernel_launch(void* const* d_in, const int* in_sizes, int n_in,
                              void* d_out, int out_size, void* d_ws, size_t ws_size,
                              hipStream_t stream) {
  const float* x   = (const float*)d_in[0];
  const int* label = (const int*)d_in[1];
  float* out = (float*)d_out;

  char* ws = (char*)d_ws;
  size_t off = 0;
  auto alloc = [&](size_t bytes) -> void* {
    void* p = ws + off;
    off = (off + bytes + 255) & ~(size_t)255;
    return p;
  };
  double* EA = (double*)alloc((size_t)Bn * Mn * sizeof(double));
  double* E  = (double*)alloc((size_t)Mn * Mn * sizeof(double));
  double* tj = (double*)alloc((size_t)Bn * Bn * 16 * sizeof(double));

  kA_gemm<<<dim3(12, 13), 256, 0, stream>>>(x, EA, E);
  kB_pairs<<<dim3(Bn, Bn), 1024, 0, stream>>>(EA, E, label, tj);
  kC_final<<<1, 1024, 0, stream>>>(tj, label, out);
}

// Round 7
// 91.921 us; speedup vs baseline: 2.4148x; 1.1192x over previous
//
#include <hip/hip_runtime.h>
#include <math.h>

#define Bn 48
#define Ln 17
#define Dn 256
#define Mn 768        // Bn*(Ln-1)
#define NS 2          // kB slices per i (blocks = NS*Bn, all active)
#define LDA 76        // LDS row stride for kA staging

// exp(e) for e in [0, ~0.02]; rel err < 3e-15
static __device__ __forceinline__ double pexp(double e) {
  return 1.0 + e*(1.0 + e*(0.5 + e*((1.0/6.0) + e*((1.0/24.0) + e*(1.0/120.0)))));
}

// block-wide sum over 16 waves (1024 threads); safe for back-to-back reuse
static __device__ __forceinline__ double blockReduce16(double v, double* red) {
  __syncthreads();
  #pragma unroll
  for (int o = 32; o > 0; o >>= 1) v += __shfl_down(v, o, 64);
  int lane = threadIdx.x & 63, wid = threadIdx.x >> 6;
  if (lane == 0) red[wid] = v;
  __syncthreads();
  double r = 0.0;
  #pragma unroll
  for (int w = 0; w < 16; ++w) r += red[w];
  return r;
}

// logical row m (0..815: 48 anchors then 768 tokens) -> row in x (B,L,D)
static __device__ __forceinline__ int src_row_m(int m) {
  if (m < Bn) return m * Ln;                 // (b, l=0)
  int t = m - Bn;
  return (t >> 4) * Ln + (t & 15) + 1;       // (b, l=1..16)
}
static __device__ __forceinline__ int src_row_n(int n) {
  return (n >> 4) * Ln + (n & 15) + 1;
}

// ---------- kA: fused normalize + GEMM + exp epilogue; zeroes out[0] ----------
__global__ __launch_bounds__(256) void kA_gemm(const float* __restrict__ x,
                                               double* __restrict__ EA,
                                               double* __restrict__ E,
                                               float* __restrict__ out) {
  __shared__ float As[16][LDA];
  __shared__ float Bs[16][LDA];
  __shared__ float nA[64], nB[64];
  int tid = threadIdx.x;
  if (blockIdx.x == 0 && blockIdx.y == 0 && tid == 0) out[0] = 0.f;
  int m0 = blockIdx.y * 64, n0 = blockIdx.x * 64;
  int r  = tid >> 2, cq = tid & 3;
  int mrow = m0 + r;
  int gm = (mrow < 816) ? src_row_m(mrow) : 0;
  int gn = src_row_n(n0 + r);
  const float* pa = x + gm * Dn + cq * 4;
  const float* pb = x + gn * Dn + cq * 4;
  float4 ra = *(const float4*)pa;
  float4 rb = *(const float4*)pb;
  float ssa = 0.f, ssb = 0.f;
  float c[4][4];
  #pragma unroll
  for (int i = 0; i < 4; ++i)
    #pragma unroll
    for (int j = 0; j < 4; ++j) c[i][j] = 0.f;
  int tx = tid & 15, ty = tid >> 4;

  for (int t = 0; t < 16; ++t) {
    __syncthreads();
    int kb = cq * 4;
    As[kb+0][r] = ra.x; As[kb+1][r] = ra.y; As[kb+2][r] = ra.z; As[kb+3][r] = ra.w;
    Bs[kb+0][r] = rb.x; Bs[kb+1][r] = rb.y; Bs[kb+2][r] = rb.z; Bs[kb+3][r] = rb.w;
    ssa += ra.x*ra.x + ra.y*ra.y + ra.z*ra.z + ra.w*ra.w;
    ssb += rb.x*rb.x + rb.y*rb.y + rb.z*rb.z + rb.w*rb.w;
    __syncthreads();
    if (t < 15) {
      ra = *(const float4*)(pa + (t + 1) * 16);
      rb = *(const float4*)(pb + (t + 1) * 16);
    }
    #pragma unroll
    for (int k = 0; k < 16; ++k) {
      float4 a4 = *(const float4*)&As[k][ty * 4];
      float4 b4 = *(const float4*)&Bs[k][tx * 4];
      float av[4] = {a4.x, a4.y, a4.z, a4.w};
      float bv[4] = {b4.x, b4.y, b4.z, b4.w};
      #pragma unroll
      for (int i = 0; i < 4; ++i)
        #pragma unroll
        for (int j = 0; j < 4; ++j) c[i][j] = fmaf(av[i], bv[j], c[i][j]);
    }
  }
  ssa += __shfl_xor(ssa, 1, 64); ssa += __shfl_xor(ssa, 2, 64);
  ssb += __shfl_xor(ssb, 1, 64); ssb += __shfl_xor(ssb, 2, 64);
  if (cq == 0) { nA[r] = ssa; nB[r] = ssb; }
  __syncthreads();
  double ia[4], ib[4];
  #pragma unroll
  for (int i = 0; i < 4; ++i) ia[i] = 1.0 / sqrt((double)nA[ty * 4 + i]);
  #pragma unroll
  for (int j = 0; j < 4; ++j) ib[j] = 1.0 / sqrt((double)nB[tx * 4 + j]);
  #pragma unroll
  for (int i = 0; i < 4; ++i) {
    int m = m0 + ty * 4 + i;
    if (m >= 816) continue;
    #pragma unroll
    for (int j = 0; j < 4; ++j) {
      int n = n0 + tx * 4 + j;
      double ev = exp((double)c[i][j] * ia[i] * ib[j]);   // T = 1.0
      if (m < Bn) EA[m * Mn + n] = ev;
      else        E[(m - Bn) * Mn + n] = ev;
    }
  }
}

// ---------- kB: grid (NS, Bn) — per-i setup + sweep positive bj; atomic out ----
// t(i,j) = (A - Bv)/C - D2*inv_s2 + Evi
__global__ __launch_bounds__(1024, 2) void kB_i(const double* __restrict__ EA,
                                                const double* __restrict__ E,
                                                const int* __restrict__ label,
                                                float* __restrict__ out) {
  __shared__ double2 sp[Mn];                 // {a masked, pexp(a) masked}
  __shared__ double red[16];
  __shared__ int lab[Bn];
  int slice = blockIdx.x, i = blockIdx.y;
  int tid = threadIdx.x;
  int lane = tid & 63, w = tid >> 6;
  if (tid < Bn) lab[tid] = label[tid];
  __syncthreads();
  int li = lab[i];

  // ---- per-i setup from EA row (tid<768 holds one element in-register) ----
  bool has = (tid < Mn);
  bool neg = has && (lab[tid >> 4] != li);
  double eav = has ? EA[i * Mn + tid] : 0.0;
  double s1 = blockReduce16(neg ? eav : 0.0, red);
  double ci = 1.0 / s1;                      // exp(-log_denom)
  double a = ci * eav;
  double p = pexp(a);
  if (has) { sp[tid].x = neg ? a : 0.0; sp[tid].y = neg ? p : 0.0; }
  double t2a = blockReduce16(neg ? p : 0.0, red);
  double t2b = blockReduce16(neg ? p * a : 0.0, red);
  double inv_s2 = 1.0 / t2a;
  double Evi = t2b * inv_s2;
  unsigned long long nm = __ballot(lane < Bn && lab[lane] != li);
  int cnt = 64 - __popcll(nm | 0xFFFF000000000000ull);   // same-label batches

  // ---- sweep positive bj's of this slice; wave w handles j = bj*16 + w ----
  int kb0 = lane >> 4;
  double tsum = 0.0;
  for (int bj = slice; bj < Bn; bj += NS) {
    if (lab[bj] != li) continue;             // uniform LDS test, no divergence
    const double* Ej = E + (bj * 16 + w) * Mn + lane;
    double Evv[12];
    #pragma unroll
    for (int it = 0; it < 12; ++it) Evv[it] = Ej[64 * it];
    double A = 0.0, Bv = 0.0, C = 0.0, D2 = 0.0;
    #pragma unroll
    for (int it = 0; it < 12; ++it) {
      double m = (double)((nm >> (kb0 + 4 * it)) & 1ull);
      double e = ci * Evv[it];
      double wx = pexp(e);
      double wm = wx * m;
      double2 s = sp[lane + 64 * it];
      A  = fma(wm, e, A);
      Bv = fma(wx, s.x, Bv);                 // s.x pre-masked
      C += wm;
      D2 = fma(s.y, e, D2);                  // s.y pre-masked
    }
    #pragma unroll
    for (int o = 32; o > 0; o >>= 1) {
      A  += __shfl_xor(A,  o, 64);
      Bv += __shfl_xor(Bv, o, 64);
      C  += __shfl_xor(C,  o, 64);
      D2 += __shfl_xor(D2, o, 64);
    }
    tsum += (A - Bv) / C - D2 * inv_s2 + Evi;
  }

  // ---- fold 16 wave partials, one float atomic per block ----
  __syncthreads();
  if (lane == 0) red[w] = tsum;
  __syncthreads();
  if (tid == 0) {
    double s = 0.0;
    #pragma unroll
    for (int ww = 0; ww < 16; ++ww) s += red[ww];
    // contribution = 0.5 * s / (Bn * P_i), P_i = 16*cnt  ->  s / (1536*cnt)
    atomicAdd(out, (float)(s / (1536.0 * (double)cnt)));
  }
}

extern "C" void kernel_launch(void* const* d_in, const int* in_sizes, int n_in,
                              void* d_out, int out_size, void* d_ws, size_t ws_size,
                              hipStream_t stream) {
  const float* x   = (const float*)d_in[0];
  const int* label = (const int*)d_in[1];
  float* out = (float*)d_out;

  char* ws = (char*)d_ws;
  size_t off = 0;
  auto alloc = [&](size_t bytes) -> void* {
    void* p = ws + off;
    off = (off + bytes + 255) & ~(size_t)255;
    return p;
  };
  double* EA = (double*)alloc((size_t)Bn * Mn * sizeof(double));
  double* E  = (double*)alloc((size_t)Mn * Mn * sizeof(double));

  kA_gemm<<<dim3(12, 13), 256, 0, stream>>>(x, EA, E, out);
  kB_i<<<dim3(NS, Bn), 1024, 0, stream>>>(EA, E, label, out);
}